// Round 1
// baseline (217.613 us; speedup 1.0000x reference)
//
#include <hip/hip_runtime.h>
#include <stdint.h>

typedef __attribute__((ext_vector_type(4))) float f32x4;
typedef __attribute__((ext_vector_type(8))) short s16x8;

__device__ __forceinline__ unsigned int f2bf_u(float x) {
  union { float f; unsigned int u; } v; v.f = x;
  return (v.u + 0x7FFFu + ((v.u >> 16) & 1u)) >> 16;   // RNE
}
__device__ __forceinline__ unsigned int pack_bf2(float lo, float hi) {
  return f2bf_u(lo) | (f2bf_u(hi) << 16);
}
__device__ __forceinline__ float bflo(unsigned int w) { return __uint_as_float(w << 16); }
__device__ __forceinline__ float bfhi(unsigned int w) { return __uint_as_float(w & 0xFFFF0000u); }

union FragU { uint4 u; s16x8 s; };

// Convert W_qk (16384 f32) and W_v (16384 f32) to bf16 in workspace.
__global__ void __launch_bounds__(256) prep_weights(const float* __restrict__ Wqk,
                                                    const float* __restrict__ Wv,
                                                    uint16_t* __restrict__ wsqk,
                                                    uint16_t* __restrict__ wsv) {
  int i = blockIdx.x * 256 + threadIdx.x;
  if (i < 16384) {
    wsqk[i] = (uint16_t)f2bf_u(Wqk[i]);
  } else if (i < 32768) {
    int j = i - 16384;
    wsv[j] = (uint16_t)f2bf_u(Wv[j]);
  }
}

// One WG: b = blk>>8, n0 = (blk&255)*4. Handles 4 n's (j = n_local*16 + k, 64 cols).
__global__ void __launch_bounds__(256, 4) attn_kernel(
    const float* __restrict__ X,          // (16,128,1024,16) f32
    const float* __restrict__ bqk,        // (128) f32
    const float* __restrict__ bv,         // (128) f32
    const unsigned int* __restrict__ wqk, // 128x128 bf16 as 8192 words
    const unsigned int* __restrict__ wv,  // 128x128 bf16 as 8192 words
    float* __restrict__ out)              // (16,1024,128) f32
{
  __shared__ unsigned int sXt[64 * 68];   // Xt[j][c] bf16 pairs, row stride 68 words (272B)
  __shared__ unsigned int sAP[64 * 68];   // stage A natural (stride 32 words) -> Pt[j][o] (stride 68) -> sY
  __shared__ float sa[4][16];
  __shared__ float sS[4];

  const int t    = threadIdx.x;
  const int lane = t & 63;
  const int w    = t >> 6;      // wave 0..3
  const int nn   = lane & 15;
  const int quad = lane >> 4;

  const int blk = blockIdx.x;
  const int b   = blk >> 8;
  const int n0  = (blk & 255) << 2;

  // ---- Stage A: global fp32 -> sAP natural bf16 [c][j], row stride 32 words ----
  {
    const int j4 = t & 15;      // float4 index within 64-col row
    const int cb = t >> 4;      // 16 c's per pass
    #pragma unroll
    for (int it = 0; it < 8; ++it) {
      const int c = cb + it * 16;
      const float4 v = *reinterpret_cast<const float4*>(
          X + ((size_t)(b * 128 + c) * 1024 + n0) * 16 + j4 * 4);
      uint2 pk;
      pk.x = pack_bf2(v.x, v.y);
      pk.y = pack_bf2(v.z, v.w);
      *reinterpret_cast<uint2*>(&sAP[c * 32 + j4 * 2]) = pk;
    }
  }
  __syncthreads();

  // ---- Stage B: transpose -> sXt[j][c] (bank-even via ch rotation) ----
  {
    const int jp = t & 31;      // j pair (2jp, 2jp+1)
    const int cg = t >> 5;      // 0..7
    #pragma unroll
    for (int s = 0; s < 2; ++s) {
      const int ch = (cg + 8 * s + jp) & 15;   // 8-c chunk index
      unsigned int wd[8];
      #pragma unroll
      for (int i = 0; i < 8; ++i) wd[i] = sAP[(ch * 8 + i) * 32 + jp];
      uint4 lo, hi;
      lo.x = (wd[0] & 0xFFFFu) | (wd[1] << 16);
      lo.y = (wd[2] & 0xFFFFu) | (wd[3] << 16);
      lo.z = (wd[4] & 0xFFFFu) | (wd[5] << 16);
      lo.w = (wd[6] & 0xFFFFu) | (wd[7] << 16);
      hi.x = (wd[0] >> 16) | (wd[1] & 0xFFFF0000u);
      hi.y = (wd[2] >> 16) | (wd[3] & 0xFFFF0000u);
      hi.z = (wd[4] >> 16) | (wd[5] & 0xFFFF0000u);
      hi.w = (wd[6] >> 16) | (wd[7] & 0xFFFF0000u);
      *reinterpret_cast<uint4*>(&sXt[(2 * jp) * 68 + ch * 4]) = lo;
      *reinterpret_cast<uint4*>(&sXt[(2 * jp + 1) * 68 + ch * 4]) = hi;
    }
  }
  __syncthreads();

  // ---- Stage 1: P = Wqk @ X + bqk  ->  Pt[j][o] bf16 in sAP (stride 68) ----
  {
    const int o0 = w * 32;
    f32x4 acc[2][4];
    #pragma unroll
    for (int mt = 0; mt < 2; ++mt) {
      const float4 bq = *reinterpret_cast<const float4*>(bqk + o0 + mt * 16 + quad * 4);
      #pragma unroll
      for (int tt = 0; tt < 4; ++tt) {
        acc[mt][tt][0] = bq.x; acc[mt][tt][1] = bq.y;
        acc[mt][tt][2] = bq.z; acc[mt][tt][3] = bq.w;
      }
    }
    #pragma unroll
    for (int ks = 0; ks < 4; ++ks) {
      FragU af[2], bf[4];
      #pragma unroll
      for (int mt = 0; mt < 2; ++mt)
        af[mt].u = *reinterpret_cast<const uint4*>(wqk + (o0 + mt * 16 + nn) * 64 + ks * 16 + quad * 4);
      #pragma unroll
      for (int tt = 0; tt < 4; ++tt)
        bf[tt].u = *reinterpret_cast<const uint4*>(&sXt[(tt * 16 + nn) * 68 + ks * 16 + quad * 4]);
      #pragma unroll
      for (int mt = 0; mt < 2; ++mt)
        #pragma unroll
        for (int tt = 0; tt < 4; ++tt)
          acc[mt][tt] = __builtin_amdgcn_mfma_f32_16x16x32_bf16(af[mt].s, bf[tt].s, acc[mt][tt], 0, 0, 0);
    }
    // Epilogue: write Pt[j][o] as bf16 pairs; reg-pair parity trick for bank-evenness.
    #pragma unroll
    for (int mt = 0; mt < 2; ++mt) {
      #pragma unroll
      for (int tt = 0; tt < 4; ++tt) {
        const int j = tt * 16 + nn;
        const unsigned int pw0 = pack_bf2(acc[mt][tt][0], acc[mt][tt][1]);
        const unsigned int pw1 = pack_bf2(acc[mt][tt][2], acc[mt][tt][3]);
        #pragma unroll
        for (int s = 0; s < 2; ++s) {
          const int rp = (nn + s) & 1;
          sAP[j * 68 + (o0 >> 1) + mt * 8 + quad * 2 + rp] = rp ? pw1 : pw0;
        }
      }
    }
  }
  __syncthreads();

  // ---- Stage 2: E = Q^T K per n (wave w -> n=w); softmax over k; a -> sa ----
  {
    const int n = w;
    f32x4 e; e[0] = 0.f; e[1] = 0.f; e[2] = 0.f; e[3] = 0.f;
    #pragma unroll
    for (int ks = 0; ks < 2; ++ks) {
      FragU qa, kb;
      qa.u = *reinterpret_cast<const uint4*>(&sAP[(n * 16 + nn) * 68 + ks * 16 + quad * 4]);        // Q cols 0..63
      kb.u = *reinterpret_cast<const uint4*>(&sAP[(n * 16 + nn) * 68 + 32 + ks * 16 + quad * 4]);   // K cols 64..127
      e = __builtin_amdgcn_mfma_f32_16x16x32_bf16(qa.s, kb.s, e, 0, 0, 0);
    }
    float p[4], sm[4];
    #pragma unroll
    for (int r = 0; r < 4; ++r) {
      float l = e[r] * 0.125f;                         // /sqrt(64)
      float mx = l;
      mx = fmaxf(mx, __shfl_xor(mx, 1));
      mx = fmaxf(mx, __shfl_xor(mx, 2));
      mx = fmaxf(mx, __shfl_xor(mx, 4));
      mx = fmaxf(mx, __shfl_xor(mx, 8));
      float pe = __expf(l - mx);
      float ss = pe;
      ss += __shfl_xor(ss, 1);
      ss += __shfl_xor(ss, 2);
      ss += __shfl_xor(ss, 4);
      ss += __shfl_xor(ss, 8);
      p[r] = pe; sm[r] = ss;
    }
    if (nn == 0) {
      #pragma unroll
      for (int r = 0; r < 4; ++r) sa[n][quad * 4 + r] = p[r] / sm[r];
    }
  }
  __syncthreads();

  // ---- Stage Y: y_n = X_n a_n -> sY (bf16, rows 0..3; rows 4..15 zero); S_n ----
  unsigned int* sY = sAP;   // 16*68 words, Pt is dead now
  {
    // zero pad rows 4..15
    for (int idx = t; idx < 12 * 68; idx += 256) sY[4 * 68 + idx] = 0u;
    const int cp = t & 63;     // c pair (2cp, 2cp+1)
    const int n  = t >> 6;
    float a[16];
    float S = 0.f;
    #pragma unroll
    for (int k = 0; k < 16; ++k) { a[k] = sa[n][k]; S += a[k]; }
    float y0 = 0.f, y1 = 0.f;
    #pragma unroll
    for (int k = 0; k < 16; ++k) {
      const unsigned int xw = sXt[(n * 16 + k) * 68 + cp];
      y0 += a[k] * bflo(xw);
      y1 += a[k] * bfhi(xw);
    }
    sY[n * 68 + cp] = pack_bf2(y0, y1);
    if (cp == 0) sS[n] = S;
  }
  __syncthreads();

  // ---- Stage 3: Out = Wv @ Y + bv * S ----
  {
    #pragma unroll
    for (int i = 0; i < 2; ++i) {
      const int ct = w * 2 + i;   // c-out tile, 8 tiles over 4 waves
      f32x4 z; z[0] = 0.f; z[1] = 0.f; z[2] = 0.f; z[3] = 0.f;
      #pragma unroll
      for (int ks = 0; ks < 4; ++ks) {
        FragU av, by;
        av.u = *reinterpret_cast<const uint4*>(wv + (ct * 16 + nn) * 64 + ks * 16 + quad * 4);
        by.u = *reinterpret_cast<const uint4*>(&sY[nn * 68 + ks * 16 + quad * 4]);
        z = __builtin_amdgcn_mfma_f32_16x16x32_bf16(av.s, by.s, z, 0, 0, 0);
      }
      if (nn < 4) {
        const float4 bvv = *reinterpret_cast<const float4*>(bv + ct * 16 + quad * 4);
        const float S = sS[nn];
        float4 o4;
        o4.x = z[0] + bvv.x * S;
        o4.y = z[1] + bvv.y * S;
        o4.z = z[2] + bvv.z * S;
        o4.w = z[3] + bvv.w * S;
        *reinterpret_cast<float4*>(out + (size_t)(b * 1024 + n0 + nn) * 128 + ct * 16 + quad * 4) = o4;
      }
    }
  }
}

extern "C" void kernel_launch(void* const* d_in, const int* in_sizes, int n_in,
                              void* d_out, int out_size, void* d_ws, size_t ws_size,
                              hipStream_t stream) {
  (void)in_sizes; (void)n_in; (void)out_size; (void)ws_size;
  const float* X   = (const float*)d_in[0];
  const float* Wqk = (const float*)d_in[1];
  const float* bqk = (const float*)d_in[2];
  const float* Wv  = (const float*)d_in[3];
  const float* bv  = (const float*)d_in[4];
  // d_in[5] = qk_dim (=64), compile-time constant here.

  uint16_t* wsqk = (uint16_t*)d_ws;           // 32 KB
  uint16_t* wsv  = wsqk + 16384;              // 32 KB

  prep_weights<<<128, 256, 0, stream>>>(Wqk, Wv, wsqk, wsv);
  attn_kernel<<<4096, 256, 0, stream>>>(X, bqk, bv,
                                        (const unsigned int*)wsqk,
                                        (const unsigned int*)wsv,
                                        (float*)d_out);
}